// Round 12
// baseline (136.025 us; speedup 1.0000x reference)
//
#include <hip/hip_runtime.h>
#include <hip/hip_bf16.h>
#include <math.h>

#define BB 64
#define DD 512
#define NMSE (64*32*512)   // 1048576 elements
#define NGEMM 512          // GEMM blocks
#define NMSEB 64           // fused MSE blocks
#define BK 64
#define PAD 72             // shorts/row: 144B stride, 16B-aligned, ~free conflicts
#define KITERS (DD/BK)     // 8

typedef __attribute__((ext_vector_type(8)))  short v8s;   // 8 bf16 (4 VGPRs)
typedef __attribute__((ext_vector_type(16))) float v16f;  // 32x32 acc (16 f32)

__device__ inline unsigned short bfb(float f) {           // RNE f32->bf16 bits
    union { __hip_bfloat16 h; unsigned short s; } u;
    u.h = __float2bfloat16(f);
    return u.s;
}
__device__ inline float bff(unsigned short s) { return __uint_as_float(((unsigned)s) << 16); }

// convert float4 -> hi/lo bf16, store to LDS, accumulate sum-of-squares in reg
__device__ inline void cvt_store(float4 v, unsigned short* __restrict__ H,
                                 unsigned short* __restrict__ L, int off, float& ssq) {
    ssq = fmaf(v.x, v.x, ssq); ssq = fmaf(v.y, v.y, ssq);
    ssq = fmaf(v.z, v.z, ssq); ssq = fmaf(v.w, v.w, ssq);
    unsigned short h0 = bfb(v.x), h1 = bfb(v.y), h2 = bfb(v.z), h3 = bfb(v.w);
    float l0 = v.x - bff(h0), l1 = v.y - bff(h1), l2 = v.z - bff(h2), l3 = v.w - bff(h3);
    uint2 hp, lp;
    hp.x = (unsigned)h0 | ((unsigned)h1 << 16);
    hp.y = (unsigned)h2 | ((unsigned)h3 << 16);
    lp.x = (unsigned)bfb(l0) | ((unsigned)bfb(l1) << 16);
    lp.y = (unsigned)bfb(l2) | ((unsigned)bfb(l3) << 16);
    *(uint2*)&H[off] = hp;
    *(uint2*)&L[off] = lp;
}

// barrier that waits ONLY lgkmcnt (LDS) — prefetch global loads stay in flight
__device__ inline void bar_lds() {
    asm volatile("s_waitcnt lgkmcnt(0)" ::: "memory");
    __builtin_amdgcn_s_barrier();
    asm volatile("" ::: "memory");
}

// ---------------- K_main: MFMA bf16x3 GEMM, depth-2 prefetch, + MSE ----------
// Blocks [0,512): per-(b,xt) GEMM. 8 waves (2x4), C-tile 64x128, BK=64.
//   Two prefetch register sets (P0 even tiles, P1 odd) -> loads issued two
//   iterations ahead (~2 MFMA phases of latency cover).
// Blocks [512,576): MSE partial sums (+ block 512 zeroes d_out for k_red2).
__global__ __launch_bounds__(512, 4) void k_main(const float* __restrict__ X,
                                                 const float* __restrict__ Y,
                                                 const float* __restrict__ P,
                                                 const float* __restrict__ M,
                                                 float* __restrict__ pm1,
                                                 float* __restrict__ pcm,
                                                 float* __restrict__ msep,
                                                 float* __restrict__ out) {
    __shared__ unsigned short Ah[64 * PAD], Al[64 * PAD];    // [row][k]
    __shared__ unsigned short Bh[128 * PAD], Bl[128 * PAD];  // [col][k]
    __shared__ float sSqX[64], sSqY[128];
    __shared__ float rowm[4][64];   // [wc][row]
    __shared__ float colm[2][128];  // [wr][col]
    __shared__ float sred[512];

    int tid = threadIdx.x;

    // ---------------- fused MSE path ----------------
    if (blockIdx.x >= NGEMM) {
        if (blockIdx.x == NGEMM && tid == 0) out[0] = 0.0f;  // init for atomics
        const float4* p4 = (const float4*)P;
        const float4* m4 = (const float4*)M;
        int n4 = NMSE / 4;
        float s = 0.0f;
        for (int i = (blockIdx.x - NGEMM) * 512 + tid; i < n4; i += NMSEB * 512) {
            float4 a = p4[i], b = m4[i];
            float dx = a.x - b.x, dy = a.y - b.y, dz = a.z - b.z, dw = a.w - b.w;
            s += dx*dx + dy*dy + dz*dz + dw*dw;
        }
        sred[tid] = s;
        __syncthreads();
        for (int o = 256; o > 0; o >>= 1) {
            if (tid < o) sred[tid] += sred[tid + o];
            __syncthreads();
        }
        if (tid == 0) msep[blockIdx.x - NGEMM] = sred[0];
        return;
    }

    // ---------------- GEMM path ----------------
    // XCD-aware swizzle: co-locate one b's x-tiles per XCD (Y slice L2-hot)
    int d  = blockIdx.x;
    int g  = d & 7;
    int s_ = d >> 3;
    int b  = g * 8 + (s_ & 7);
    int xt = s_ >> 3;
    int x0 = xt * 64;

    int w    = tid >> 6;       // 8 waves
    int wr   = w >> 2;         // 0..1: rows 32*wr..+31
    int wc   = w & 3;          // 0..3: cols 32*wc..+31
    int lane = tid & 63;
    int ln31 = lane & 31;
    int hi   = lane >> 5;
    int g8   = hi * 8;
    int arow = 32 * wr + ln31;
    int bcol = 32 * wc + ln31;

    // staging map: 512 threads; row r gets 16 threads (q = float4 index in BK=64)
    int r  = tid >> 4;          // 0..31
    int q  = tid & 15;          // 0..15
    const float* gA0 = &X[((size_t)(x0 + r) * BB + b) * DD + q * 4];
    const float* gA1 = &X[((size_t)(x0 + r + 32) * BB + b) * DD + q * 4];
    const float* gB0 = &Y[((size_t)(r)      * BB + b) * DD + q * 4];
    const float* gB1 = &Y[((size_t)(r + 32) * BB + b) * DD + q * 4];
    const float* gB2 = &Y[((size_t)(r + 64) * BB + b) * DD + q * 4];
    const float* gB3 = &Y[((size_t)(r + 96) * BB + b) * DD + q * 4];

    v16f acc;
    #pragma unroll
    for (int t = 0; t < 16; ++t) acc[t] = 0.0f;
    float sqA0 = 0.0f, sqA1 = 0.0f, sqB0 = 0.0f, sqB1 = 0.0f, sqB2 = 0.0f, sqB3 = 0.0f;

    // depth-2 prefetch: P0 = even tiles, P1 = odd tiles
    float4 p0a0 = *(const float4*)(gA0), p0a1 = *(const float4*)(gA1);
    float4 p0b0 = *(const float4*)(gB0), p0b1 = *(const float4*)(gB1);
    float4 p0b2 = *(const float4*)(gB2), p0b3 = *(const float4*)(gB3);
    float4 p1a0 = *(const float4*)(gA0 + BK), p1a1 = *(const float4*)(gA1 + BK);
    float4 p1b0 = *(const float4*)(gB0 + BK), p1b1 = *(const float4*)(gB1 + BK);
    float4 p1b2 = *(const float4*)(gB2 + BK), p1b3 = *(const float4*)(gB3 + BK);

    #pragma unroll
    for (int it = 0; it < KITERS; it += 2) {
        // ---------- even tile: consume P0, refill P0 <- tile it+2 ----------
        cvt_store(p0a0, Ah, Al, (r)      * PAD + q * 4, sqA0);
        cvt_store(p0a1, Ah, Al, (r + 32) * PAD + q * 4, sqA1);
        cvt_store(p0b0, Bh, Bl, (r)      * PAD + q * 4, sqB0);
        cvt_store(p0b1, Bh, Bl, (r + 32) * PAD + q * 4, sqB1);
        cvt_store(p0b2, Bh, Bl, (r + 64) * PAD + q * 4, sqB2);
        cvt_store(p0b3, Bh, Bl, (r + 96) * PAD + q * 4, sqB3);
        if (it + 2 < KITERS) {
            int k0 = (it + 2) * BK;
            p0a0 = *(const float4*)(gA0 + k0); p0a1 = *(const float4*)(gA1 + k0);
            p0b0 = *(const float4*)(gB0 + k0); p0b1 = *(const float4*)(gB1 + k0);
            p0b2 = *(const float4*)(gB2 + k0); p0b3 = *(const float4*)(gB3 + k0);
        }
        bar_lds();   // tile visible; vmcnt NOT drained
        #pragma unroll
        for (int ks = 0; ks < 4; ++ks) {
            int koff = ks * 16 + g8;
            v8s ah = *(const v8s*)&Ah[arow * PAD + koff];
            v8s al = *(const v8s*)&Al[arow * PAD + koff];
            v8s bh = *(const v8s*)&Bh[bcol * PAD + koff];
            v8s bl = *(const v8s*)&Bl[bcol * PAD + koff];
            acc = __builtin_amdgcn_mfma_f32_32x32x16_bf16(ah, bh, acc, 0, 0, 0);
            acc = __builtin_amdgcn_mfma_f32_32x32x16_bf16(ah, bl, acc, 0, 0, 0);
            acc = __builtin_amdgcn_mfma_f32_32x32x16_bf16(al, bh, acc, 0, 0, 0);
        }
        bar_lds();   // frag reads done before next overwrite

        // ---------- odd tile: consume P1, refill P1 <- tile it+3 ----------
        cvt_store(p1a0, Ah, Al, (r)      * PAD + q * 4, sqA0);
        cvt_store(p1a1, Ah, Al, (r + 32) * PAD + q * 4, sqA1);
        cvt_store(p1b0, Bh, Bl, (r)      * PAD + q * 4, sqB0);
        cvt_store(p1b1, Bh, Bl, (r + 32) * PAD + q * 4, sqB1);
        cvt_store(p1b2, Bh, Bl, (r + 64) * PAD + q * 4, sqB2);
        cvt_store(p1b3, Bh, Bl, (r + 96) * PAD + q * 4, sqB3);
        if (it + 3 < KITERS) {
            int k0 = (it + 3) * BK;
            p1a0 = *(const float4*)(gA0 + k0); p1a1 = *(const float4*)(gA1 + k0);
            p1b0 = *(const float4*)(gB0 + k0); p1b1 = *(const float4*)(gB1 + k0);
            p1b2 = *(const float4*)(gB2 + k0); p1b3 = *(const float4*)(gB3 + k0);
        }
        bar_lds();
        #pragma unroll
        for (int ks = 0; ks < 4; ++ks) {
            int koff = ks * 16 + g8;
            v8s ah = *(const v8s*)&Ah[arow * PAD + koff];
            v8s al = *(const v8s*)&Al[arow * PAD + koff];
            v8s bh = *(const v8s*)&Bh[bcol * PAD + koff];
            v8s bl = *(const v8s*)&Bl[bcol * PAD + koff];
            acc = __builtin_amdgcn_mfma_f32_32x32x16_bf16(ah, bh, acc, 0, 0, 0);
            acc = __builtin_amdgcn_mfma_f32_32x32x16_bf16(ah, bl, acc, 0, 0, 0);
            acc = __builtin_amdgcn_mfma_f32_32x32x16_bf16(al, bh, acc, 0, 0, 0);
        }
        bar_lds();
    }

    // ---- ssq reduction: 16 threads share a row ----
    #pragma unroll
    for (int o = 1; o < 16; o <<= 1) {
        sqA0 += __shfl_xor(sqA0, o, 64);
        sqA1 += __shfl_xor(sqA1, o, 64);
        sqB0 += __shfl_xor(sqB0, o, 64);
        sqB1 += __shfl_xor(sqB1, o, 64);
        sqB2 += __shfl_xor(sqB2, o, 64);
        sqB3 += __shfl_xor(sqB3, o, 64);
    }
    if (q == 0) {
        sSqX[r]      = sqA0;  sSqX[r + 32] = sqA1;
        sSqY[r]      = sqB0;  sSqY[r + 32] = sqB1;
        sSqY[r + 64] = sqB2;  sSqY[r + 96] = sqB3;
    }
    __syncthreads();
    if (tid < 64) sSqX[tid] = 1.0f / fmaxf(sqrtf(sSqX[tid]), 1e-12f);
    else if (tid < 192) sSqY[tid - 64] = 1.0f / fmaxf(sqrtf(sSqY[tid - 64]), 1e-12f);
    __syncthreads();

    // ---- post-scale: C/D layout (m74/m101): col=lane&31,
    //      row=(t&3)+8*(t>>2)+4*(lane>>5) ----
    float sy = sSqY[32 * wc + ln31];
    #pragma unroll
    for (int t = 0; t < 16; ++t) {
        float sx = sSqX[32 * wr + (t & 3) + 8 * (t >> 2) + 4 * hi];
        acc[t] *= sx * sy;
    }

    // ---- row reduction: per-row max over this wave's 32 cols ----
    #pragma unroll
    for (int t = 0; t < 16; ++t) {
        float m = acc[t];
        #pragma unroll
        for (int o = 1; o < 32; o <<= 1) m = fmaxf(m, __shfl_xor(m, o, 64));
        if (ln31 == 0) {
            int rowid = (t & 3) + 8 * (t >> 2) + 4 * hi;
            rowm[wc][32 * wr + rowid] = m;
        }
    }

    // ---- col reduction: per-col max over this wave's 32 rows ----
    float cm = acc[0];
    #pragma unroll
    for (int t = 1; t < 16; ++t) cm = fmaxf(cm, acc[t]);
    cm = fmaxf(cm, __shfl_xor(cm, 32, 64));
    if (lane < 32) colm[wr][32 * wc + lane] = cm;
    __syncthreads();

    if (tid < 64) {
        float v = fmaxf(fmaxf(rowm[0][tid], rowm[1][tid]),
                        fmaxf(rowm[2][tid], rowm[3][tid]));   // max over 128 cols
        #pragma unroll
        for (int o = 1; o < 64; o <<= 1) v = fminf(v, __shfl_xor(v, o, 64));
        if (tid == 0) pm1[b * 8 + xt] = v;                    // min over 64 rows
    }
    if (tid >= 64 && tid < 192) {
        int c = tid - 64;
        pcm[(size_t)(b * 8 + xt) * 128 + c] = fmaxf(colm[0][c], colm[1][c]);
    }
}

// ---------------- K_red2: per-batch hausdorff + loss + combine (64 blocks) ---
__global__ __launch_bounds__(256) void k_red2(const float* __restrict__ pm1,
                                              const float* __restrict__ pcm,
                                              const float* __restrict__ msep,
                                              const float* __restrict__ prob,
                                              const int* __restrict__ label,
                                              float* __restrict__ out) {
    __shared__ float red[128];
    int tid = threadIdx.x;
    int b = blockIdx.x;

    if (tid < 128) {
        float cm = -1e30f;
        #pragma unroll
        for (int t = 0; t < 8; ++t)
            cm = fmaxf(cm, pcm[(size_t)(b * 8 + t) * 128 + tid]);
        red[tid] = cm;   // per-col max over all 512 rows
    }
    __syncthreads();
    if (tid < 64) {
        float v = fminf(red[tid], red[tid + 64]);
        #pragma unroll
        for (int o = 1; o < 64; o <<= 1) v = fminf(v, __shfl_xor(v, o, 64));  // m2
        if (tid == 0) {
            float m1 = 1e30f;
            #pragma unroll
            for (int t = 0; t < 8; ++t) m1 = fminf(m1, pm1[b * 8 + t]);
            float m = fminf(m1, v);
            float hd = sqrtf(fmaxf(2.0f - 2.0f * m, 0.0f));
            float lab = (float)label[b];
            float rel = fmaxf(0.5f - hd, 0.0f);
            float contrast = lab * hd * hd + (1.0f - lab) * rel * rel;
            float pv = prob[b];
            float logp   = fmaxf(logf(pv), -100.0f);
            float log1mp = fmaxf(log1pf(-pv), -100.0f);
            float bce = -(lab * logp + (1.0f - lab) * log1mp);
            atomicAdd(out, (contrast + bce) * (1.0f / 64.0f)
                           + msep[b] * (1.0f / (float)NMSE));
        }
    }
}

// ---------------- launch -----------------------------------------------------
extern "C" void kernel_launch(void* const* d_in, const int* in_sizes, int n_in,
                              void* d_out, int out_size, void* d_ws, size_t ws_size,
                              hipStream_t stream) {
    const float* X = (const float*)d_in[0]; // encoded_frame [512,64,512]
    const float* Y = (const float*)d_in[1]; // encoded_word  [128,64,512]
    const float* P = (const float*)d_in[2]; // predict_mask_feature
    const float* M = (const float*)d_in[3]; // masked_feature
    const float* pv = (const float*)d_in[4];
    const int*   lb = (const int*)d_in[5];
    float* out = (float*)d_out;

    float* ws = (float*)d_ws;
    float* pm1   = ws;            // 512
    float* pcm   = ws + 512;      // 65536
    float* msep  = ws + 66048;    // 64

    k_main<<<NGEMM + NMSEB, 512, 0, stream>>>(X, Y, P, M, pm1, pcm, msep, out);
    k_red2<<<BB, 256, 0, stream>>>(pm1, pcm, msep, pv, lb, out);
}